// Round 4
// baseline (289.876 us; speedup 1.0000x reference)
//
#include <hip/hip_runtime.h>

// LSTM_67980742362036: 2-layer LSTM (B=4096, T=200, I=32, H=6) + linear head.
// One 64-thread block (1 wave) per batch element; 4096 waves = 4 waves/SIMD
// (hard occupancy cap: B is the only parallel dim of the scan).
//
// R4: the scan is LATENCY-bound (~1990 cyc/iter measured vs ~110 issue) ->
// remove cross-lane latency from the serial chain:
//   - Gate rows re-indexed lane = 4*unit + gate (i,f,g,o per quad). The
//     i/f/g/o gather is now 4x v_mov_dpp quad_perm (~2-4 cyc each) instead
//     of 4x ds_bpermute (~120 cyc LDS each). c/h become quad-replicated.
//   - h broadcast: 12x v_readlane (VALU latency) from quad-base lanes.
//   - No barriers at all (single wave: DS pipe is in-order per wave).
//   - kg==0 guard peeled out of the loop (L1 phantom step).
//   - Phase P: 3 row-groups x 2 K-halves with xr[4] -> peak ~44 live VGPRs,
//     no spills (R3 still wrote 10.4 MB scratch). x re-read 3x from L1/L2.
// LDS: only the xp buffer (65 rows x 28 dwords = 7.3 KB).

#define BATCH 4096
#define TLEN  200
#define ISZ   32
#define HSZ   6
#define GSZ   24      // 4*H
#define TCH   64      // timesteps per chunk (Phase P tile)
#define XPITCH 28     // padded LDS row stride (dwords)
#define XROWS (TCH + 1)  // +1 garbage row for unconditional prefetch

__device__ __forceinline__ float fast_sig(float x) {
    // 1/(1+exp(-x)); v_exp + v_rcp. |rel err| ~1e-7 vs 3.7e-3 threshold.
    return __builtin_amdgcn_rcpf(1.0f + __expf(-x));
}
__device__ __forceinline__ float rl(float v, int l) {
    return __int_as_float(__builtin_amdgcn_readlane(__float_as_int(v), l));
}
template <int CTRL>
__device__ __forceinline__ float qperm(float v) {
    // quad_perm DPP: every lane gets element CTRL-pattern of its 4-lane quad.
    return __int_as_float(__builtin_amdgcn_mov_dpp(__float_as_int(v), CTRL, 0xf, 0xf, true));
}

__global__ void __launch_bounds__(64)
lstm_fused(
    const float* __restrict__ x,
    const float* __restrict__ Wih0, const float* __restrict__ Whh0,
    const float* __restrict__ bih0, const float* __restrict__ bhh0,
    const float* __restrict__ Wih1, const float* __restrict__ Whh1,
    const float* __restrict__ bih1, const float* __restrict__ bhh1,
    const float* __restrict__ Wlin, const float* __restrict__ blin,
    float* __restrict__ out)
{
    __shared__ __align__(16) float xp_lds[XROWS * XPITCH];  // L0 gate pre-acts [t][row]

    const int lane = threadIdx.x;
    const int b    = blockIdx.x;

    // ---------------- lane roles (interleaved gate layout) ----------------
    // lane = half*32 + 4*j + p : unit j (0..5), gate p (0=i,1=f,2=g,3=o).
    // Gate row in original W order: r = 6*p + j.
    const bool loHalf = (lane < 32);
    const int  p  = lane & 3;
    const int  jq = (lane & 31) >> 2;          // quad index within half (0..7)
    const int  j  = (jq < HSZ) ? jq : 0;       // idle quads 6,7 alias unit 0
    const int  r  = 6 * p + j;                 // gate row (0..23)

    float WA[HSZ], WB[HSZ];
    float base1 = 0.0f;
#pragma unroll
    for (int k = 0; k < HSZ; ++k) { WA[k] = 0.0f; WB[k] = 0.0f; }
    if (loHalf) {
#pragma unroll
        for (int k = 0; k < HSZ; ++k) WA[k] = Whh0[r * HSZ + k];
    } else {
#pragma unroll
        for (int k = 0; k < HSZ; ++k) { WA[k] = Wih1[r * HSZ + k]; WB[k] = Whh1[r * HSZ + k]; }
        base1 = bih1[r] + bhh1[r];
    }
    // gate p==2 is the cell gate -> tanh(x) = 2*sig(2x)-1
    const float mg  = (p == 2) ? 2.0f : 1.0f;
    const float sg  = (p == 2) ? 2.0f : 1.0f;
    const float tgc = (p == 2) ? -1.0f : 0.0f;

    float c = 0.0f, h = 0.0f;   // quad-replicated cell/hidden state

    for (int t0 = 0; t0 < TLEN; t0 += TCH) {
        const int tcl = min(TCH, TLEN - t0);

        // ------------- Phase P: x-projection (register-lean) -------------
        // 3 groups of 8 rows x 2 K-halves: peak live ~ xr[4](16)+acc[8](8)
        // + persistent(~20) < 56 VGPRs -> no scratch.
        {
            const int tIdx = min(t0 + lane, TLEN - 1);   // clamped tail rows never read
            const float4* xrow = (const float4*)(x + ((size_t)b * TLEN + tIdx) * ISZ);
#pragma unroll
            for (int grp = 0; grp < 3; ++grp) {
                float acc[8];
#pragma unroll
                for (int rr = 0; rr < 8; ++rr)
                    acc[rr] = bih0[grp * 8 + rr] + bhh0[grp * 8 + rr];   // uniform
#pragma unroll
                for (int kh = 0; kh < 2; ++kh) {
                    float4 xr[4];
#pragma unroll
                    for (int q = 0; q < 4; ++q) xr[q] = xrow[4 * kh + q];
#pragma unroll
                    for (int rr = 0; rr < 8; ++rr) {
                        const float4* wrow =
                            (const float4*)(Wih0 + (grp * 8 + rr) * ISZ + kh * 16);  // uniform
#pragma unroll
                        for (int q = 0; q < 4; ++q) {
                            float4 w = wrow[q];
                            acc[rr] += w.x * xr[q].x + w.y * xr[q].y
                                     + w.z * xr[q].z + w.w * xr[q].w;
                        }
                    }
                }
                *(float4*)&xp_lds[lane * XPITCH + 8 * grp] =
                    make_float4(acc[0], acc[1], acc[2], acc[3]);
                *(float4*)&xp_lds[lane * XPITCH + 8 * grp + 4] =
                    make_float4(acc[4], acc[5], acc[6], acc[7]);
            }
        }
        // no barrier: single wave, DS ops are in-order per wave.

        // ------------- Phase S: scan (DPP gather, guard-free) -------------
        const bool lastChunk = (t0 + TCH >= TLEN);
        const int  iters = tcl + (lastChunk ? 1 : 0);  // +1 drain iter for L1
        float xp_cur = xp_lds[r];                      // row 0 of this chunk
        int   it0 = 0;

        if (t0 == 0) {
            // peeled kg==0: L0's first step (h1=h2=0); L1 must stay zero.
            const float g  = loHalf ? xp_cur : base1;
            const float a  = fmaf(sg, fast_sig(mg * g), tgc);
            const float iq = qperm<0x00>(a);
            const float gq = qperm<0xAA>(a);
            const float oq = qperm<0xFF>(a);
            const float cn = iq * gq;                            // f*c0 = 0
            const float th = fmaf(2.0f, fast_sig(2.0f * cn), -1.0f);
            const float hn = oq * th;
            c = loHalf ? cn : 0.0f;
            h = loHalf ? hn : 0.0f;
            xp_cur = xp_lds[XPITCH + r];                         // row 1
            it0 = 1;
        }

        for (int it = it0; it < iters; ++it) {
            // h broadcast from quad-base lanes (VALU readlane, low latency)
            const float h10 = rl(h, 0),  h11 = rl(h, 4),  h12 = rl(h, 8);
            const float h13 = rl(h, 12), h14 = rl(h, 16), h15 = rl(h, 20);
            const float h20 = rl(h, 32), h21 = rl(h, 36), h22 = rl(h, 40);
            const float h23 = rl(h, 44), h24 = rl(h, 48), h25 = rl(h, 52);

            // prefetch next xp row (garbage on final prefetch; never consumed)
            const float xp_nxt = xp_lds[(it + 1) * XPITCH + r];

            // gate pre-activation (4 parallel fma chains)
            const float g0 = loHalf ? xp_cur : base1;
            float a0 = fmaf(WA[0], h10, fmaf(WA[2], h12, fmaf(WA[4], h14, g0)));
            float a1 = fmaf(WA[1], h11, fmaf(WA[3], h13, WA[5] * h15));
            float b0 = fmaf(WB[0], h20, fmaf(WB[2], h22, WB[4] * h24));
            float b1 = fmaf(WB[1], h21, fmaf(WB[3], h23, WB[5] * h25));
            const float g = (a0 + a1) + (b0 + b1);
            const float a = fmaf(sg, fast_sig(mg * g), tgc);

            // i/f/g/o gather within the quad: 4x DPP (~2-4 cyc each)
            const float iq = qperm<0x00>(a);
            const float fq = qperm<0x55>(a);
            const float gq = qperm<0xAA>(a);
            const float oq = qperm<0xFF>(a);

            // cell/hidden update, quad-replicated (drain-iter garbage on L0
            // and idle quads is never read)
            c = fmaf(fq, c, iq * gq);
            const float th = fmaf(2.0f, fast_sig(2.0f * c), -1.0f);  // tanh(c)
            h = oq * th;

            xp_cur = xp_nxt;
        }
    }

    // Linear head on final h2 (quads of upper half), uniform via readlane.
    float s = blin[0];
#pragma unroll
    for (int k = 0; k < HSZ; ++k) s = fmaf(Wlin[k], rl(h, 32 + 4 * k), s);
    if (lane == 0) out[b] = s;
}

extern "C" void kernel_launch(void* const* d_in, const int* in_sizes, int n_in,
                              void* d_out, int out_size, void* d_ws, size_t ws_size,
                              hipStream_t stream) {
    const float* x    = (const float*)d_in[0];
    const float* Wih0 = (const float*)d_in[1];
    const float* Whh0 = (const float*)d_in[2];
    const float* bih0 = (const float*)d_in[3];
    const float* bhh0 = (const float*)d_in[4];
    const float* Wih1 = (const float*)d_in[5];
    const float* Whh1 = (const float*)d_in[6];
    const float* bih1 = (const float*)d_in[7];
    const float* bhh1 = (const float*)d_in[8];
    const float* Wlin = (const float*)d_in[9];
    const float* blin = (const float*)d_in[10];
    float* out = (float*)d_out;

    lstm_fused<<<BATCH, 64, 0, stream>>>(x, Wih0, Whh0, bih0, bhh0,
                                         Wih1, Whh1, bih1, bhh1,
                                         Wlin, blin, out);
}